// Round 9
// baseline (20.336 us; speedup 1.0000x reference)
//
#include <hip/hip_runtime.h>
#include <math.h>

#define HH 256
#define WW 256
#define NPTS 1024
#define RANK 6
#define NC 128
#define PIX (HH * WW)
#define PSTRIDE 20        // floats per packed gaussian (17 used, 5x vf4)
#define MAXG 256          // per-row survivor capacity (worst row ~60 expected)
#define SEG 64            // per-wave idx segment capacity (8 waves x 128 gids)

typedef float vf4 __attribute__((ext_vector_type(4)));

__device__ __forceinline__ float softplus_f(float x) {
    return fmaxf(x, 0.0f) + log1pf(__expf(-fabsf(x)));
}

// ---------------------------------------------------------------------------
// 256 blocks x 512 threads; block = one full image row (256 px). Eval is
// split 2-way per pixel across threads; render store phase: wave w writes
// channels [w*16, w*16+16) -- each store instruction is 64 lanes x 16B =
// one channel's ENTIRE row = 1 KB contiguous (fill-kernel granularity).
// Plain stores (no NT): the harness fill kernel sustains 6.5 TB/s this way.
// ---------------------------------------------------------------------------
__global__ __launch_bounds__(512) void fused_kernel(
    const float* __restrict__ xyz, const float* __restrict__ chol,
    const float* __restrict__ fdc, const float* __restrict__ gfreq,
    const float* __restrict__ gwt, const float* __restrict__ opac,
    const float* __restrict__ lU, const float* __restrict__ lV,
    const float* __restrict__ lS, const float* __restrict__ em,
    float* __restrict__ render, float* __restrict__ abund,
    float* __restrict__ Eout)
{
    __shared__ float Els[NC * 8];              // 4 KB   E[c][r] (8-padded)
    __shared__ float glist[MAXG * PSTRIDE];    // 20 KB  packed survivors
    __shared__ int   idxl[8 * SEG];            // 2 KB   per-wave segments
    __shared__ int   wcnt[8];
    __shared__ float accT[RANK * 512];         // 12 KB  partial accumulators
    __shared__ float accR[RANK * 256];         // 6 KB   reduced (clamped)

    const int t  = threadIdx.x;
    const int y  = blockIdx.x;                 // row
    const int wv = t >> 6;                     // 0..7
    const int ln = t & 63;
    const int pxl = t & 255;                   // eval pixel x
    const int half = t >> 8;                   // 0/1: gaussian half
    const float px = (float)pxl + 0.5f;
    const float py = (float)y + 0.5f;

    // ---- E staging; block 0 also writes Eout ----
    {
        float scale = 0.1f * tanhf(lS[0]);
        for (int i = t; i < RANK * NC; i += 512) {
            int r = i >> 7; int c = i & 127;
            float dot = lU[r * 2] * lV[c] + lU[r * 2 + 1] * lV[NC + c];
            float e = fmaxf(em[i] + scale * tanhf(dot), 1e-6f);
            Els[c * 8 + r] = e;
            if (y == 0) Eout[i] = e;
        }
    }

    // ---- per-wave cull (no barriers): wave wv owns gids [wv*128, +128) ----
    const float tymin = (float)y, tymax = (float)(y + 1);
    {
        int cnt = 0;                           // wave-uniform running count
        const int gbase = wv * 128;
        for (int k = 0; k < 2; ++k) {
            const int gid = gbase + k * 64 + ln;
            float cy = (tanhf(xyz[gid * 2 + 1]) * 0.5f + 0.5f) * (float)HH;
            float l2 = chol[gid * 3 + 1];
            float l3 = chol[gid * 3 + 2] + 0.5f;
            float c = l2 * l2 + l3 * l3;
            float ry = 6.0f * sqrtf(c);        // sqrt(2*18*c)
            // row spans full x-range: x-cull is vacuous; y-test only
            bool hit = (cy - ry <= tymax) && (cy + ry >= tymin);
            unsigned long long m = __ballot(hit);
            if (hit) {
                int pos = cnt + __popcll(m & ((1ull << ln) - 1ull));
                if (pos < SEG) idxl[wv * SEG + pos] = gid;
            }
            cnt += __popcll(m);
        }
        if (ln == 0) wcnt[wv] = min(cnt, SEG);
    }
    __syncthreads();                                    // barrier 1

    int off[8];
    {
        int s = 0;
#pragma unroll
        for (int w = 0; w < 8; ++w) { off[w] = s; s += wcnt[w]; }
    }
    int T = off[7] + wcnt[7];
    if (T > MAXG) T = MAXG;

    // ---- packed params for survivors ----
    // g0={cx,cy,ca,cb} g1={cc,fx0,fy0,fx1} g2={fy1,gw0,gw1,f0}
    // g3={f1,f2,f3,f4} g4={f5,-,-,-}
    for (int j = t; j < T; j += 512) {
        int w = 0;
#pragma unroll
        for (int q = 1; q < 8; ++q) { if (j >= off[q]) w = q; }
        const int n = idxl[w * SEG + (j - off[w])];
        float cx = (tanhf(xyz[n * 2 + 0]) * 0.5f + 0.5f) * (float)WW;
        float cy = (tanhf(xyz[n * 2 + 1]) * 0.5f + 0.5f) * (float)HH;
        float l1 = chol[n * 3 + 0] + 0.5f;
        float l2 = chol[n * 3 + 1];
        float l3 = chol[n * 3 + 2] + 0.5f;
        float a = l1 * l1, bb = l1 * l2, c = l2 * l2 + l3 * l3;
        float inv = 1.0f / (a * c - bb * bb);
        float* g = glist + j * PSTRIDE;
        g[0] = cx; g[1] = cy;
        g[2] = c * inv; g[3] = -bb * inv; g[4] = a * inv;
        g[5] = __expf(gfreq[n * 4 + 0]);
        g[6] = __expf(gfreq[n * 4 + 1]);
        g[7] = __expf(gfreq[n * 4 + 2]);
        g[8] = __expf(gfreq[n * 4 + 3]);
        g[9]  = 1.0f / (1.0f + __expf(-gwt[n * 2 + 0]));
        g[10] = 1.0f / (1.0f + __expf(-gwt[n * 2 + 1]));
        float op = opac[n];
#pragma unroll
        for (int r = 0; r < RANK; ++r)
            g[11 + r] = softplus_f(fdc[n * RANK + r]) * op;
    }
    __syncthreads();                                    // barrier 2

    // ---- eval: thread = (pixel pxl, gaussian half); vf4 LDS broadcasts ----
    float acc[RANK] = {0.f, 0.f, 0.f, 0.f, 0.f, 0.f};
    for (int i = half; i < T; i += 2) {
        const vf4* gv = (const vf4*)(glist + i * PSTRIDE);
        vf4 g0 = gv[0];
        vf4 g1 = gv[1];
        vf4 g2 = gv[2];
        float dx = px - g0.x;
        float dy = py - g0.y;
        float sigma = 0.5f * (g0.z * dx * dx + g1.x * dy * dy) + g0.w * dx * dy;
        vf4 g3 = gv[3];
        vf4 g4 = gv[4];
        float wm = __expf(-sigma) *
                   (1.0f + g2.y * __cosf(g1.y * dx + g1.z * dy)
                         + g2.z * __cosf(g1.w * dx + g2.x * dy));
        wm = (sigma >= 0.0f) ? wm : 0.0f;   // cndmask, no branch
        acc[0] = fmaf(wm, g2.w, acc[0]);
        acc[1] = fmaf(wm, g3.x, acc[1]);
        acc[2] = fmaf(wm, g3.y, acc[2]);
        acc[3] = fmaf(wm, g3.z, acc[3]);
        acc[4] = fmaf(wm, g3.w, acc[4]);
        acc[5] = fmaf(wm, g4.x, acc[5]);
    }
#pragma unroll
    for (int r = 0; r < RANK; ++r)
        accT[r * 512 + t] = acc[r];
    __syncthreads();                                    // barrier 3

    // ---- reduce halves + clamp ----
    for (int v = t; v < RANK * 256; v += 512) {
        int r = v >> 8, u = v & 255;
        float s = accT[r * 512 + u] + accT[r * 512 + 256 + u];
        accR[v] = fmaxf(s, 0.0f);
    }
    __syncthreads();                                    // barrier 4

    // ---- abundance: 1536 contiguous floats = 384 vf4 stores ----
    if (t < 384) {
        vf4 q;
#pragma unroll
        for (int k = 0; k < 4; ++k) {
            int v = t * 4 + k;
            int pl = v / 6;
            int r  = v - pl * 6;
            q[k] = accR[r * 256 + pl];
        }
        *((vf4*)(abund + (size_t)y * WW * RANK) + t) = q;
    }

    // ---- render: wave w -> channels [w*16, w*16+16); each store instr =
    //      64 lanes x vf4 = the channel's full 1 KB row, contiguous ----
    vf4 ab[RANK];
#pragma unroll
    for (int r = 0; r < RANK; ++r)
        ab[r] = *(const vf4*)(accR + r * 256 + ln * 4);

    float* rp = render + (size_t)y * WW + (size_t)ln * 4;
#pragma unroll
    for (int i = 0; i < 16; ++i) {
        const int c = wv * 16 + i;
        const vf4 e0 = *(const vf4*)(Els + c * 8);       // broadcast
        const vf4 e1 = *(const vf4*)(Els + c * 8 + 4);
        vf4 o = ab[0] * e0.x;
        o += ab[1] * e0.y;
        o += ab[2] * e0.z;
        o += ab[3] * e0.w;
        o += ab[4] * e1.x;
        o += ab[5] * e1.y;
        *((vf4*)(rp + (size_t)c * PIX)) = o;
    }
}

extern "C" void kernel_launch(void* const* d_in, const int* in_sizes, int n_in,
                              void* d_out, int out_size, void* d_ws, size_t ws_size,
                              hipStream_t stream)
{
    const float* xyz             = (const float*)d_in[0];
    const float* cholesky        = (const float*)d_in[1];
    const float* features_dc     = (const float*)d_in[2];
    const float* gabor_freqs     = (const float*)d_in[3];
    const float* gabor_weights   = (const float*)d_in[4];
    const float* lora_U          = (const float*)d_in[5];
    const float* lora_V          = (const float*)d_in[6];
    const float* lora_scale_logit= (const float*)d_in[7];
    const float* opacity         = (const float*)d_in[8];
    const float* endmember       = (const float*)d_in[9];

    float* out    = (float*)d_out;
    float* render = out;                               // NC*PIX
    float* abund  = out + (size_t)NC * PIX;            // PIX*RANK
    float* Eout   = abund + (size_t)PIX * RANK;        // RANK*NC

    fused_kernel<<<HH, 512, 0, stream>>>(
        xyz, cholesky, features_dc, gabor_freqs, gabor_weights, opacity,
        lora_U, lora_V, lora_scale_logit, endmember, render, abund, Eout);
}

// Round 10
// 17.393 us; speedup vs baseline: 1.1692x; 1.1692x over previous
//
#include <hip/hip_runtime.h>
#include <math.h>

#define HH 256
#define WW 256
#define NPTS 1024
#define RANK 6
#define NC 128
#define PIX (HH * WW)
#define PSTRIDE 20        // floats per packed gaussian (17 used, 5x vf4)
#define MAXG 160          // per-strip survivor capacity (worst ~40 expected)
#define SEG 128           // per-wave idx segment capacity

typedef float vf4 __attribute__((ext_vector_type(4)));

__device__ __forceinline__ float softplus_f(float x) {
    return fmaxf(x, 0.0f) + log1pf(__expf(-fabsf(x)));
}

// tanh via one HW exp: tanh(x) = (e^{2x}-1)/(e^{2x}+1). Clamp keeps e finite.
// |err| ~1e-6 -> center shift ~1e-4 px; absmax margin is 10x. Used in cull
// (conservative bbox), pack, and E (args are O(0.01)).
__device__ __forceinline__ float fast_tanh(float x) {
    float xc = fminf(fmaxf(x, -15.0f), 15.0f);
    float e = __expf(2.0f * xc);
    return (e - 1.0f) / (e + 1.0f);
}

// 1024 blocks = 1024 strips of 64x1 px; each block computes ALL 128 channels
// for its strip. Eval runs once per pixel, split 4-ways across waves.
// (R8 structure verbatim; only tanhf -> fast_tanh.)
__global__ __launch_bounds__(256) void fused_kernel(
    const float* __restrict__ xyz, const float* __restrict__ chol,
    const float* __restrict__ fdc, const float* __restrict__ gfreq,
    const float* __restrict__ gwt, const float* __restrict__ opac,
    const float* __restrict__ lU, const float* __restrict__ lV,
    const float* __restrict__ lS, const float* __restrict__ em,
    float* __restrict__ render, float* __restrict__ abund,
    float* __restrict__ Eout)
{
    __shared__ float Els[NC * 8];              // 4 KB    E[c][r] (8-padded)
    __shared__ float glist[MAXG * PSTRIDE];    // 12.8 KB packed survivors
    __shared__ int   idxl[4 * SEG];            // 2 KB    per-wave segments
    __shared__ int   wcnt[4];
    __shared__ float accT[RANK * 4 * 64];      // 6 KB    partial accumulators
    __shared__ float accR[RANK * 64];          // 1.5 KB  reduced (clamped)

    const int t    = threadIdx.x;
    const int tile = blockIdx.x;               // 1024 strips of 64x1
    const int tx   = (tile & 3) * 64;
    const int ty   = tile >> 2;
    const int wv   = t >> 6;
    const int ln   = t & 63;
    const float px = (float)(tx + ln) + 0.5f;  // eval pixel: x = tx + ln
    const float py = (float)ty + 0.5f;

    // ---- E staging (3 entries/thread); block 0 also writes Eout ----
    {
        float scale = 0.1f * fast_tanh(lS[0]);
#pragma unroll
        for (int k = 0; k < 3; ++k) {
            int i = k * 256 + t;               // i < 768
            int r = i >> 7; int c = i & 127;
            float dot = lU[r * 2] * lV[c] + lU[r * 2 + 1] * lV[NC + c];
            float e = fmaxf(em[i] + scale * fast_tanh(dot), 1e-6f);
            Els[c * 8 + r] = e;
            if (tile == 0) Eout[i] = e;
        }
    }

    // ---- per-wave cull (no barriers): wave wv owns gids [wv*256, +256) ----
    const float txmin = (float)tx, txmax = (float)(tx + 64);
    const float tymin = (float)ty, tymax = (float)(ty + 1);
    {
        int cnt = 0;                           // wave-uniform running count
        const int gbase = wv * 256;
        for (int k = 0; k < 4; ++k) {
            const int gid = gbase + k * 64 + ln;
            float cx = (fast_tanh(xyz[gid * 2 + 0]) * 0.5f + 0.5f) * (float)WW;
            float cy = (fast_tanh(xyz[gid * 2 + 1]) * 0.5f + 0.5f) * (float)HH;
            float l1 = chol[gid * 3 + 0] + 0.5f;
            float l2 = chol[gid * 3 + 1];
            float l3 = chol[gid * 3 + 2] + 0.5f;
            float a = l1 * l1;
            float c = l2 * l2 + l3 * l3;
            float rx = 6.0f * sqrtf(a) + 0.1f;   // sqrt(2*18*a) + approx margin
            float ry = 6.0f * sqrtf(c) + 0.1f;
            bool hit = (cx - rx <= txmax) && (cx + rx >= txmin) &&
                       (cy - ry <= tymax) && (cy + ry >= tymin);
            unsigned long long m = __ballot(hit);
            if (hit) {
                int pos = cnt + __popcll(m & ((1ull << ln) - 1ull));
                if (pos < SEG) idxl[wv * SEG + pos] = gid;
            }
            cnt += __popcll(m);
        }
        if (ln == 0) wcnt[wv] = min(cnt, SEG);
    }
    __syncthreads();                                    // barrier 1

    const int c0 = wcnt[0], c1 = wcnt[1], c2 = wcnt[2], c3 = wcnt[3];
    const int o1 = c0, o2 = c0 + c1, o3 = o2 + c2;
    int T = o3 + c3;
    if (T > MAXG) T = MAXG;

    // ---- packed params for survivors ----
    // g0={cx,cy,ca,cb} g1={cc,fx0,fy0,fx1} g2={fy1,gw0,gw1,f0}
    // g3={f1,f2,f3,f4} g4={f5,-,-,-}
    for (int j = t; j < T; j += 256) {
        int w, o;
        if (j < o1)      { w = 0; o = j; }
        else if (j < o2) { w = 1; o = j - o1; }
        else if (j < o3) { w = 2; o = j - o2; }
        else             { w = 3; o = j - o3; }
        const int n = idxl[w * SEG + o];
        float cx = (fast_tanh(xyz[n * 2 + 0]) * 0.5f + 0.5f) * (float)WW;
        float cy = (fast_tanh(xyz[n * 2 + 1]) * 0.5f + 0.5f) * (float)HH;
        float l1 = chol[n * 3 + 0] + 0.5f;
        float l2 = chol[n * 3 + 1];
        float l3 = chol[n * 3 + 2] + 0.5f;
        float a = l1 * l1, bb = l1 * l2, c = l2 * l2 + l3 * l3;
        float inv = 1.0f / (a * c - bb * bb);
        float* g = glist + j * PSTRIDE;
        g[0] = cx; g[1] = cy;
        g[2] = c * inv; g[3] = -bb * inv; g[4] = a * inv;
        g[5] = __expf(gfreq[n * 4 + 0]);
        g[6] = __expf(gfreq[n * 4 + 1]);
        g[7] = __expf(gfreq[n * 4 + 2]);
        g[8] = __expf(gfreq[n * 4 + 3]);
        g[9]  = 1.0f / (1.0f + __expf(-gwt[n * 2 + 0]));
        g[10] = 1.0f / (1.0f + __expf(-gwt[n * 2 + 1]));
        float op = opac[n];
#pragma unroll
        for (int r = 0; r < RANK; ++r)
            g[11 + r] = softplus_f(fdc[n * RANK + r]) * op;
    }
    __syncthreads();                                    // barrier 2

    // ---- eval: thread = (pixel ln, gaussian-quarter wv) ----
    float acc[RANK] = {0.f, 0.f, 0.f, 0.f, 0.f, 0.f};
    for (int i = wv; i < T; i += 4) {
        const vf4* gv = (const vf4*)(glist + i * PSTRIDE);
        vf4 g0 = gv[0];
        vf4 g1 = gv[1];
        vf4 g2 = gv[2];
        float dx = px - g0.x;
        float dy = py - g0.y;
        float sigma = 0.5f * (g0.z * dx * dx + g1.x * dy * dy) + g0.w * dx * dy;
        vf4 g3 = gv[3];
        vf4 g4 = gv[4];
        float wm = __expf(-sigma) *
                   (1.0f + g2.y * __cosf(g1.y * dx + g1.z * dy)
                         + g2.z * __cosf(g1.w * dx + g2.x * dy));
        wm = (sigma >= 0.0f) ? wm : 0.0f;   // cndmask, no branch
        acc[0] = fmaf(wm, g2.w, acc[0]);
        acc[1] = fmaf(wm, g3.x, acc[1]);
        acc[2] = fmaf(wm, g3.y, acc[2]);
        acc[3] = fmaf(wm, g3.z, acc[3]);
        acc[4] = fmaf(wm, g3.w, acc[4]);
        acc[5] = fmaf(wm, g4.x, acc[5]);
    }
#pragma unroll
    for (int r = 0; r < RANK; ++r)
        accT[r * 256 + t] = acc[r];
    __syncthreads();                                    // barrier 3

    // ---- reduce 4 quarters + clamp ----
    for (int v = t; v < RANK * 64; v += 256) {
        int r = v >> 6, u = v & 63;
        const float* row = accT + r * 256;
        float s = (row[u] + row[64 + u]) + (row[128 + u] + row[192 + u]);
        accR[v] = fmaxf(s, 0.0f);
    }
    __syncthreads();                                    // barrier 4

    // ---- abundance: 384 contiguous floats = 96 vf4 NT stores ----
    if (t < 96) {
        vf4 q;
#pragma unroll
        for (int k = 0; k < 4; ++k) {
            int v = t * 4 + k;
            int pl = v / 6;
            int r  = v - pl * 6;
            q[k] = accR[r * 64 + pl];
        }
        __builtin_nontemporal_store(
            q, (vf4*)(abund + (size_t)(ty * WW + tx) * RANK) + t);
    }

    // ---- render: wave covers 4 channels x 256B per store instr ----
    const int pxo = (ln & 15) * 4;
    vf4 ab[RANK];
#pragma unroll
    for (int r = 0; r < RANK; ++r)
        ab[r] = *(const vf4*)(accR + r * 64 + pxo);

    float* rp = render + ty * WW + tx + pxo;
#pragma unroll
    for (int i = 0; i < 8; ++i) {
        const int cl = wv * 32 + i * 4 + (ln >> 4);
        const vf4 e0 = *(const vf4*)(Els + cl * 8);      // broadcast x16
        const vf4 e1 = *(const vf4*)(Els + cl * 8 + 4);
        vf4 o = ab[0] * e0.x;
        o += ab[1] * e0.y;
        o += ab[2] * e0.z;
        o += ab[3] * e0.w;
        o += ab[4] * e1.x;
        o += ab[5] * e1.y;
        __builtin_nontemporal_store(o, (vf4*)(rp + (size_t)cl * PIX));
    }
}

extern "C" void kernel_launch(void* const* d_in, const int* in_sizes, int n_in,
                              void* d_out, int out_size, void* d_ws, size_t ws_size,
                              hipStream_t stream)
{
    const float* xyz             = (const float*)d_in[0];
    const float* cholesky        = (const float*)d_in[1];
    const float* features_dc     = (const float*)d_in[2];
    const float* gabor_freqs     = (const float*)d_in[3];
    const float* gabor_weights   = (const float*)d_in[4];
    const float* lora_U          = (const float*)d_in[5];
    const float* lora_V          = (const float*)d_in[6];
    const float* lora_scale_logit= (const float*)d_in[7];
    const float* opacity         = (const float*)d_in[8];
    const float* endmember       = (const float*)d_in[9];

    float* out    = (float*)d_out;
    float* render = out;                               // NC*PIX
    float* abund  = out + (size_t)NC * PIX;            // PIX*RANK
    float* Eout   = abund + (size_t)PIX * RANK;        // RANK*NC

    fused_kernel<<<1024, 256, 0, stream>>>(
        xyz, cholesky, features_dc, gabor_freqs, gabor_weights, opacity,
        lora_U, lora_V, lora_scale_logit, endmember, render, abund, Eout);
}